// Round 3
// baseline (261.324 us; speedup 1.0000x reference)
//
#include <hip/hip_runtime.h>
#include <stdint.h>

// Problem constants: B=4, C=256, H=W=64 -> HW=4096, vis=1024
#define B_   4
#define C_   256
#define HW_  4096
#define VIS_ 1024
#define KE_  768      // expanded K: [hi,hi,lo] x [hi,lo,hi] f16 split
#define NT_  48       // total K-tiles across all b: 4 batches x 12 tiles

using half8   = __attribute__((ext_vector_type(8))) _Float16;
using floatx4 = __attribute__((ext_vector_type(4))) float;

__device__ __forceinline__ unsigned mapf(float v) {
    unsigned u = __float_as_uint(v);
    return (u & 0x80000000u) ? ~u : (u | 0x80000000u);
}

__global__ void init_ws_kernel(unsigned long long* ws, int n) {
    int i = blockIdx.x * blockDim.x + threadIdx.x;
    if (i < n) ws[i] = 0ull;
}

__global__ void finalize_kernel(const unsigned long long* __restrict__ ws,
                                float* __restrict__ out1, int n) {
    int i = blockIdx.x * blockDim.x + threadIdx.x;
    if (i < n) {
        unsigned kinv = (unsigned)(ws[i] & 0xFFFFFFFFull);
        out1[i] = (float)(HW_ - 1 - (int)kinv);
    }
}

// ---------------- f16-split MFMA path ----------------

// Transpose + split: src[b][c][hw] fp32 -> dst[b][hw][768] f16 with
// A segments [hi,hi,lo], B segments [hi,lo,hi]. Also zeroes the keys
// workspace (fused init: blocks with y==0&&z==0 cover exactly B_*HW_ keys).
__global__ __launch_bounds__(256) void split_transpose_kernel(
    const float* __restrict__ Q, const float* __restrict__ K,
    _Float16* __restrict__ Aexp, _Float16* __restrict__ Bexp,
    unsigned long long* __restrict__ keys)
{
    __shared__ float tile[64][65];   // [c][hw], pad 65 to break 8-col bank aliasing
    const int t = threadIdx.x;
    if (blockIdx.y == 0 && blockIdx.z == 0)
        keys[blockIdx.x * 256 + t] = 0ull;   // 64 blocks x 256 thr = 16384 = B_*HW_

    const int hw0 = blockIdx.x * 64;
    const int c0  = blockIdx.y * 64;
    const int z = blockIdx.z, b = z >> 1, which = z & 1;
    const float* src = (which ? K : Q) + (size_t)b * C_ * HW_;
    _Float16* dst = (which ? Bexp : Aexp) + (size_t)b * HW_ * KE_;

    #pragma unroll
    for (int i = 0; i < 4; ++i) {
        int c  = (t >> 4) + i * 16;
        int hw = (t & 15) * 4;
        float4 v = *(const float4*)(src + (size_t)(c0 + c) * HW_ + hw0 + hw);
        tile[c][hw] = v.x; tile[c][hw+1] = v.y; tile[c][hw+2] = v.z; tile[c][hw+3] = v.w;
    }
    __syncthreads();

    #pragma unroll
    for (int i = 0; i < 2; ++i) {
        int id  = t + i * 256;       // 0..511
        int row = id >> 3;           // hw within tile
        int c8  = (id & 7) * 8;      // c offset within 64
        half8 h8, l8;
        #pragma unroll
        for (int j = 0; j < 8; ++j) {
            float v = tile[c8 + j][row];
            _Float16 h = (_Float16)v;
            h8[j] = h;
            l8[j] = (_Float16)(v - (float)h);
        }
        _Float16* base = dst + (size_t)(hw0 + row) * KE_ + c0 + c8;
        *(half8*)(base + 0 * C_) = h8;
        *(half8*)(base + 1 * C_) = which ? l8 : h8;
        *(half8*)(base + 2 * C_) = which ? h8 : l8;
    }
}

__device__ __forceinline__ void gl2lds16(const _Float16* g, _Float16* l) {
    __builtin_amdgcn_global_load_lds(
        (const __attribute__((address_space(1))) void*)g,
        (__attribute__((address_space(3))) void*)l, 16, 0, 0);
}

// ---- 256x256 / 8-phase / counted-vmcnt GEMM, persistent over b ----
//
// Grid = 16x16 = 256 blocks = exactly 1/CU (LDS-capped anyway). Each block
// runs ONE continuous 8-phase pipeline over the flat tile sequence
// T = 0..47 (b = T/12, k-tile = T%12): no drain at b boundaries — stages
// issued during tiles 10-11 of batch b prefetch tiles 0-1 of batch b+1.
// Per-b epilogue runs between p7 and next p0 with raw LGKM0+BARRIER only
// (no __syncthreads: that emits vmcnt(0) and would drain the prefetch).
// vmcnt safety at the next VMC(4): epilogue stores/atomics are always
// OLDER than the newest 4 outstanding stage-loads, so the counted wait
// stays conservative-correct.
//
// LDS map (f16 units, 8192 per kh-half-tile of 256 rows x 32 k):
//   region = db*4 + matrix*2 + kh : db0: A0=0 A1=1 B0=2 B1=3 ; db1: A0=4 A1=5 B0=6 B1=7
// Chunk swizzle (involution on 16B chunks within a 64B row):
//   lds chunk (row, ch) holds global chunk ch ^ ((row>>1)&3)

#define BARRIER __builtin_amdgcn_s_barrier()
#define LGKM0   asm volatile("s_waitcnt lgkmcnt(0)" ::: "memory")
#define VMC(n)  asm volatile("s_waitcnt vmcnt(" #n ")" ::: "memory")
#define SCHEDB  __builtin_amdgcn_sched_barrier(0)

// one kh-half-tile: 1024 chunks of 16B; 2 global_load_lds per thread.
// LDS dest linear in lane order (gl_lds requirement); global src is
// inverse-swizzled so the read-side XOR sees data in place (rule 21).
__device__ __forceinline__ void stage_half(const _Float16* __restrict__ g,
                                           _Float16* lb, int t)
{
    #pragma unroll
    for (int j = 0; j < 2; ++j) {
        const int c   = t + j * 512;
        const int row = c >> 2;
        const int ch  = (c & 3) ^ ((row >> 1) & 3);
        gl2lds16(g + (size_t)row * KE_ + ch * 8, lb + c * 8);
    }
}

template<int DB, int KH, int MQ>
__device__ __forceinline__ void ds_load_a(const _Float16* lds, int wave_m, int s,
                                          int quad, half8 (&a)[4]) {
    const _Float16* base = lds + (DB * 4 + KH) * 8192;
    #pragma unroll
    for (int mi = 0; mi < 4; ++mi) {
        int row = wave_m * 128 + MQ * 64 + mi * 16 + s;
        int ch  = quad ^ ((row >> 1) & 3);
        a[mi] = *(const half8*)(base + row * 32 + ch * 8);
    }
}

template<int DB, int KH>
__device__ __forceinline__ void ds_load_b(const _Float16* lds, int wave_n, int s,
                                          int quad, half8 (&bfr)[4]) {
    const _Float16* base = lds + (DB * 4 + 2 + KH) * 8192;
    #pragma unroll
    for (int ni = 0; ni < 4; ++ni) {
        int col = wave_n * 64 + ni * 16 + s;
        int ch  = quad ^ ((col >> 1) & 3);
        bfr[ni] = *(const half8*)(base + col * 32 + ch * 8);
    }
}

template<int MQ>
__device__ __forceinline__ void do_mfma(const half8 (&a)[4], const half8 (&bfr)[4],
                                        floatx4 (&acc)[8][4]) {
    __builtin_amdgcn_s_setprio(1);
    #pragma unroll
    for (int mi = 0; mi < 4; ++mi)
        #pragma unroll
        for (int ni = 0; ni < 4; ++ni)
            acc[MQ * 4 + mi][ni] = __builtin_amdgcn_mfma_f32_16x16x32_f16(
                a[mi], bfr[ni], acc[MQ * 4 + mi][ni], 0, 0, 0);
    __builtin_amdgcn_s_setprio(0);
}

__global__ __launch_bounds__(512, 1) void gemm_mfma_kernel(
    const _Float16* __restrict__ Aexp, const _Float16* __restrict__ Bexp,
    float* __restrict__ out0, unsigned long long* __restrict__ keys)
{
    __shared__ __align__(16) _Float16 lds[65536];          // 128 KiB staging
    __shared__ unsigned long long red[256][4];             // 8 KiB, dedicated

    const int t      = threadIdx.x;
    const int lane   = t & 63;
    const int wave   = t >> 6;
    const int quad   = lane >> 4;
    const int s      = lane & 15;
    const int wave_m = wave >> 2;     // 0..1 -> 128 output rows
    const int wave_n = wave & 3;      // 0..3 -> 64 output cols
    const int kt = blockIdx.x, qt = blockIdx.y;

    const size_t bstr = (size_t)HW_ * KE_;
    const _Float16* Aq = Aexp + (size_t)(qt * 256) * KE_;
    const _Float16* Bk = Bexp + (size_t)(kt * 256) * KE_;

    // tile T (0..47) -> panel pointer; clamp over-the-end prefetch targets
    // to tile 47 (valid memory; those regions are never read).
    auto APTR = [&](int Tk) -> const _Float16* {
        if (Tk > NT_ - 1) Tk = NT_ - 1;
        return Aq + (size_t)(Tk / 12) * bstr + (Tk % 12) * 64;
    };
    auto BPTR = [&](int Tk) -> const _Float16* {
        if (Tk > NT_ - 1) Tk = NT_ - 1;
        return Bk + (size_t)(Tk / 12) * bstr + (Tk % 12) * 64;
    };

    // Prologue: tile0 complete (db0) + tile1 kh0 (db1); VMC(4) leaves the
    // last 2 half-tiles (tile1 kh0) in flight, tile0 fully staged.
    stage_half(APTR(0),      lds + 0 * 8192, t);
    stage_half(BPTR(0),      lds + 2 * 8192, t);
    stage_half(APTR(0) + 32, lds + 1 * 8192, t);
    stage_half(BPTR(0) + 32, lds + 3 * 8192, t);
    stage_half(APTR(1),      lds + 4 * 8192, t);
    stage_half(BPTR(1),      lds + 6 * 8192, t);
    VMC(4);
    BARRIER; SCHEDB;

    half8 a[4], bfr[4];
    floatx4 acc[8][4] = {};

    #pragma unroll 1
    for (int j = 0; j < NT_ / 2; ++j) {
        const int T = 2 * j;
        const _Float16* a1 = APTR(T + 1); const _Float16* b1 = BPTR(T + 1);
        const _Float16* a2 = APTR(T + 2); const _Float16* b2 = BPTR(T + 2);
        const _Float16* a3 = APTR(T + 3); const _Float16* b3 = BPTR(T + 3);

        // p0: compute db0/kh0/mq0, stage A(T+1)-kh1 -> region 5
        ds_load_a<0, 0, 0>(lds, wave_m, s, quad, a);
        ds_load_b<0, 0>(lds, wave_n, s, quad, bfr);
        stage_half(a1 + 32, lds + 5 * 8192, t);
        BARRIER; LGKM0;
        do_mfma<0>(a, bfr, acc);
        BARRIER;
        // p1: db0/kh0/mq1 (reuse bfr), stage B(T+1)-kh1 -> region 7
        ds_load_a<0, 0, 1>(lds, wave_m, s, quad, a);
        stage_half(b1 + 32, lds + 7 * 8192, t);
        BARRIER; LGKM0;
        do_mfma<1>(a, bfr, acc);
        BARRIER;
        // p2: db0/kh1/mq0, stage A(T+2)-kh0 -> region 0
        ds_load_a<0, 1, 0>(lds, wave_m, s, quad, a);
        ds_load_b<0, 1>(lds, wave_n, s, quad, bfr);
        stage_half(a2, lds + 0 * 8192, t);
        BARRIER; LGKM0;
        do_mfma<0>(a, bfr, acc);
        BARRIER;
        // p3: db0/kh1/mq1, stage B(T+2)-kh0 -> region 2 ; VMC(4): db1 ready
        ds_load_a<0, 1, 1>(lds, wave_m, s, quad, a);
        stage_half(b2, lds + 2 * 8192, t);
        BARRIER; LGKM0;
        do_mfma<1>(a, bfr, acc);
        VMC(4);
        BARRIER; SCHEDB;
        // p4: db1/kh0/mq0, stage A(T+2)-kh1 -> region 1
        ds_load_a<1, 0, 0>(lds, wave_m, s, quad, a);
        ds_load_b<1, 0>(lds, wave_n, s, quad, bfr);
        stage_half(a2 + 32, lds + 1 * 8192, t);
        BARRIER; LGKM0;
        do_mfma<0>(a, bfr, acc);
        BARRIER;
        // p5: db1/kh0/mq1, stage B(T+2)-kh1 -> region 3
        ds_load_a<1, 0, 1>(lds, wave_m, s, quad, a);
        stage_half(b2 + 32, lds + 3 * 8192, t);
        BARRIER; LGKM0;
        do_mfma<1>(a, bfr, acc);
        BARRIER;
        // p6: db1/kh1/mq0, stage A(T+3)-kh0 -> region 4
        ds_load_a<1, 1, 0>(lds, wave_m, s, quad, a);
        ds_load_b<1, 1>(lds, wave_n, s, quad, bfr);
        stage_half(a3, lds + 4 * 8192, t);
        BARRIER; LGKM0;
        do_mfma<0>(a, bfr, acc);
        BARRIER;
        // p7: db1/kh1/mq1, stage B(T+3)-kh0 -> region 6 ; VMC(4): db0(T+2) ready
        ds_load_a<1, 1, 1>(lds, wave_m, s, quad, a);
        stage_half(b3, lds + 6 * 8192, t);
        BARRIER; LGKM0;
        do_mfma<1>(a, bfr, acc);
        VMC(4);
        BARRIER; SCHEDB;

        // ---- per-b epilogue (T = 10, 22, 34, 46) ----
        if ((T % 12) == 10) {
            const int bq = T / 12;

            // S_vis corner (C/D layout: col=s, row=quad*4+r)
            if (qt < 4 && kt < 4) {
                #pragma unroll
                for (int mi8 = 0; mi8 < 8; ++mi8)
                    #pragma unroll
                    for (int r = 0; r < 4; ++r) {
                        int grow = qt * 256 + wave_m * 128 + mi8 * 16 + quad * 4 + r;
                        float* orow = out0 + ((size_t)bq * VIS_ + grow) * VIS_
                                    + kt * 256 + wave_n * 64;
                        #pragma unroll
                        for (int ni = 0; ni < 4; ++ni)
                            orow[ni * 16 + s] = acc[mi8][ni][r];
                    }
            }

            // fused argmax into dedicated red LDS
            #pragma unroll
            for (int mi8 = 0; mi8 < 8; ++mi8) {
                #pragma unroll
                for (int r = 0; r < 4; ++r) {
                    float best = acc[mi8][0][r];
                    int bcol = wave_n * 64 + s;
                    #pragma unroll
                    for (int ni = 1; ni < 4; ++ni) {
                        float v = acc[mi8][ni][r];
                        if (v > best) { best = v; bcol = wave_n * 64 + ni * 16 + s; }
                    }
                    int gcol = kt * 256 + bcol;
                    unsigned long long key = ((unsigned long long)mapf(best) << 32)
                                           | (unsigned)(HW_ - 1 - gcol);
                    #pragma unroll
                    for (int m = 1; m < 16; m <<= 1) {
                        unsigned long long o = __shfl_xor(key, m, 64);
                        if (o > key) key = o;
                    }
                    if (s == 0)
                        red[wave_m * 128 + mi8 * 16 + quad * 4 + r][wave & 3] = key;
                }
            }
            LGKM0; BARRIER;   // red visible; deliberately NOT __syncthreads (no vm drain)
            if (t < 256) {
                const unsigned long long* rr = red[t];
                unsigned long long k0 = rr[0], k1 = rr[1], k2 = rr[2], k3 = rr[3];
                unsigned long long m01 = k0 > k1 ? k0 : k1;
                unsigned long long m23 = k2 > k3 ? k2 : k3;
                atomicMax(&keys[(size_t)bq * HW_ + qt * 256 + t], m01 > m23 ? m01 : m23);
            }
            // reset accumulators for next batch
            #pragma unroll
            for (int mi8 = 0; mi8 < 8; ++mi8)
                #pragma unroll
                for (int ni = 0; ni < 4; ++ni)
                    acc[mi8][ni] = (floatx4){0.f, 0.f, 0.f, 0.f};
        }
    }

    VMC(0);   // drain LDS-DMA (clamped over-the-end prefetch) before exit
}

// ---------------- fp32 fallback path (round-1, known-good) ----------------
#define BT   64
#define BK   32
#define LDP  68

__global__ __launch_bounds__(256) void gemm_argmax_kernel(
    const float* __restrict__ Q, const float* __restrict__ K,
    float* __restrict__ out0, unsigned long long* __restrict__ ws)
{
    __shared__ float As[BK][LDP];
    __shared__ float Bs[BK][LDP];
    __shared__ unsigned long long red[BT][17];

    const int t  = threadIdx.x;
    const int tx = t & 15;
    const int ty = t >> 4;
    const int k0 = blockIdx.x * BT;
    const int q0 = blockIdx.y * BT;
    const int b  = blockIdx.z;

    const float* Qb = Q + (size_t)b * C_ * HW_;
    const float* Kb = K + (size_t)b * C_ * HW_;

    float acc[4][4] = {{0.f},{0.f},{0.f},{0.f}};

    for (int c0 = 0; c0 < C_; c0 += BK) {
        #pragma unroll
        for (int i = 0; i < 2; ++i) {
            int idx = i * 256 + t;
            int row = idx >> 4;
            int col = (idx & 15) * 4;
            const float4 a  = *(const float4*)(Qb + (size_t)(c0 + row) * HW_ + q0 + col);
            const float4 bv = *(const float4*)(Kb + (size_t)(c0 + row) * HW_ + k0 + col);
            *(float4*)(&As[row][col]) = a;
            *(float4*)(&Bs[row][col]) = bv;
        }
        __syncthreads();
        #pragma unroll
        for (int cc = 0; cc < BK; ++cc) {
            const float4 av = *(const float4*)(&As[cc][ty * 4]);
            const float4 bv = *(const float4*)(&Bs[cc][tx * 4]);
            const float a_[4] = {av.x, av.y, av.z, av.w};
            const float b_[4] = {bv.x, bv.y, bv.z, bv.w};
            #pragma unroll
            for (int i = 0; i < 4; ++i)
                #pragma unroll
                for (int j = 0; j < 4; ++j)
                    acc[i][j] = fmaf(a_[i], b_[j], acc[i][j]);
        }
        __syncthreads();
    }

    if (q0 < VIS_ && k0 < VIS_) {
        #pragma unroll
        for (int i = 0; i < 4; ++i) {
            float4 v = make_float4(acc[i][0], acc[i][1], acc[i][2], acc[i][3]);
            size_t off = (size_t)b * VIS_ * VIS_ + (size_t)(q0 + ty * 4 + i) * VIS_ + (k0 + tx * 4);
            *(float4*)(out0 + off) = v;
        }
    }

    #pragma unroll
    for (int i = 0; i < 4; ++i) {
        float best = acc[i][0];
        int   bj   = 0;
        #pragma unroll
        for (int j = 1; j < 4; ++j)
            if (acc[i][j] > best) { best = acc[i][j]; bj = j; }
        int kidx = k0 + tx * 4 + bj;
        unsigned long long key = ((unsigned long long)mapf(best) << 32)
                               | (unsigned)(HW_ - 1 - kidx);
        red[ty * 4 + i][tx] = key;
    }
    __syncthreads();
    if (t < BT) {
        unsigned long long best = red[t][0];
        #pragma unroll
        for (int j = 1; j < 16; ++j) {
            unsigned long long v = red[t][j];
            if (v > best) best = v;
        }
        atomicMax(&ws[(size_t)b * HW_ + q0 + t], best);
    }
}

extern "C" void kernel_launch(void* const* d_in, const int* in_sizes, int n_in,
                              void* d_out, int out_size, void* d_ws, size_t ws_size,
                              hipStream_t stream) {
    const float* Q = (const float*)d_in[0];
    const float* K = (const float*)d_in[1];
    float* out0 = (float*)d_out;
    float* out1 = out0 + (size_t)B_ * VIS_ * VIS_;

    unsigned long long* keys = (unsigned long long*)d_ws;     // 128 KB
    const size_t keys_bytes = (size_t)B_ * HW_ * 8;
    const size_t exp_elems  = (size_t)B_ * HW_ * KE_;
    const size_t need = keys_bytes + 2 * exp_elems * sizeof(_Float16);

    const int n = B_ * HW_;

    if (ws_size >= need) {
        _Float16* Aexp = (_Float16*)((char*)d_ws + keys_bytes);
        _Float16* Bexp = Aexp + exp_elems;
        split_transpose_kernel<<<dim3(HW_ / 64, C_ / 64, 2 * B_), 256, 0, stream>>>(Q, K, Aexp, Bexp, keys);
        gemm_mfma_kernel<<<dim3(HW_ / 256, HW_ / 256), 512, 0, stream>>>(Aexp, Bexp, out0, keys);
    } else {
        init_ws_kernel<<<(n + 255) / 256, 256, 0, stream>>>(keys, n);
        gemm_argmax_kernel<<<dim3(HW_ / BT, HW_ / BT, B_), 256, 0, stream>>>(Q, K, out0, keys);
    }

    finalize_kernel<<<(n + 255) / 256, 256, 0, stream>>>(keys, out1, n);
}

// Round 4
// 219.274 us; speedup vs baseline: 1.1918x; 1.1918x over previous
//
#include <hip/hip_runtime.h>
#include <stdint.h>

// Problem constants: B=4, C=256, H=W=64 -> HW=4096, vis=1024
#define B_   4
#define C_   256
#define HW_  4096
#define VIS_ 1024
#define KE_  768      // expanded K: [hi,hi,lo] x [hi,lo,hi] f16 split

using half8   = __attribute__((ext_vector_type(8))) _Float16;
using floatx4 = __attribute__((ext_vector_type(4))) float;

__device__ __forceinline__ unsigned mapf(float v) {
    unsigned u = __float_as_uint(v);
    return (u & 0x80000000u) ? ~u : (u | 0x80000000u);
}

__global__ void init_ws_kernel(unsigned long long* ws, int n) {
    int i = blockIdx.x * blockDim.x + threadIdx.x;
    if (i < n) ws[i] = 0ull;
}

__global__ void finalize_kernel(const unsigned long long* __restrict__ ws,
                                float* __restrict__ out1, int n) {
    int i = blockIdx.x * blockDim.x + threadIdx.x;
    if (i < n) {
        unsigned kinv = (unsigned)(ws[i] & 0xFFFFFFFFull);
        out1[i] = (float)(HW_ - 1 - (int)kinv);
    }
}

// ---------------- f16-split MFMA path ----------------

// Transpose + split: src[b][c][hw] fp32 -> dst[b][hw][768] f16 with
// A segments [hi,hi,lo], B segments [hi,lo,hi]. Also zeroes the keys
// workspace (fused init: blocks with y==0&&z==0 cover exactly B_*HW_ keys).
__global__ __launch_bounds__(256) void split_transpose_kernel(
    const float* __restrict__ Q, const float* __restrict__ K,
    _Float16* __restrict__ Aexp, _Float16* __restrict__ Bexp,
    unsigned long long* __restrict__ keys)
{
    __shared__ float tile[64][65];   // [c][hw], pad 65 to break 8-col bank aliasing
    const int t = threadIdx.x;
    if (blockIdx.y == 0 && blockIdx.z == 0)
        keys[blockIdx.x * 256 + t] = 0ull;   // 64 blocks x 256 thr = 16384 = B_*HW_

    const int hw0 = blockIdx.x * 64;
    const int c0  = blockIdx.y * 64;
    const int z = blockIdx.z, b = z >> 1, which = z & 1;
    const float* src = (which ? K : Q) + (size_t)b * C_ * HW_;
    _Float16* dst = (which ? Bexp : Aexp) + (size_t)b * HW_ * KE_;

    #pragma unroll
    for (int i = 0; i < 4; ++i) {
        int c  = (t >> 4) + i * 16;
        int hw = (t & 15) * 4;
        float4 v = *(const float4*)(src + (size_t)(c0 + c) * HW_ + hw0 + hw);
        tile[c][hw] = v.x; tile[c][hw+1] = v.y; tile[c][hw+2] = v.z; tile[c][hw+3] = v.w;
    }
    __syncthreads();

    #pragma unroll
    for (int i = 0; i < 2; ++i) {
        int id  = t + i * 256;       // 0..511
        int row = id >> 3;           // hw within tile
        int c8  = (id & 7) * 8;      // c offset within 64
        half8 h8, l8;
        #pragma unroll
        for (int j = 0; j < 8; ++j) {
            float v = tile[c8 + j][row];
            _Float16 h = (_Float16)v;
            h8[j] = h;
            l8[j] = (_Float16)(v - (float)h);
        }
        _Float16* base = dst + (size_t)(hw0 + row) * KE_ + c0 + c8;
        *(half8*)(base + 0 * C_) = h8;
        *(half8*)(base + 1 * C_) = which ? l8 : h8;
        *(half8*)(base + 2 * C_) = which ? h8 : l8;
    }
}

__device__ __forceinline__ void gl2lds16(const _Float16* g, _Float16* l) {
    __builtin_amdgcn_global_load_lds(
        (const __attribute__((address_space(1))) void*)g,
        (__attribute__((address_space(3))) void*)l, 16, 0, 0);
}

// ---- 256x256 / 8-phase / counted-vmcnt GEMM (T2+T3+T4+T5 stack) ----
// Round-2 schedule (131 us measured), reverted from the persistent round-3
// variant (regressed to 168 us, +28% steady-state stall, mechanism unknown).
// NEW vs round 2: T1 XCD-bijective swizzle only. Grid flattened to 1D 1024;
// block n -> work wgid = (n&7)*128 + n>>3, so each XCD (n%8) owns 128
// consecutive wgids = one batch x 8 qt-rows x all 16 kt. Per-XCD-L2 A
// working set = 8 panels x 384 KB = 3 MB <= 4 MB L2.
//
// LDS map (f16 units, 8192 per kh-half-tile of 256 rows x 32 k):
//   region = db*4 + matrix*2 + kh : db0: A0=0 A1=1 B0=2 B1=3 ; db1: A0=4 A1=5 B0=6 B1=7
// Chunk swizzle (involution on 16B chunks within a 64B row):
//   lds chunk (row, ch) holds global chunk ch ^ ((row>>1)&3)

#define BARRIER __builtin_amdgcn_s_barrier()
#define LGKM0   asm volatile("s_waitcnt lgkmcnt(0)" ::: "memory")
#define VMC(n)  asm volatile("s_waitcnt vmcnt(" #n ")" ::: "memory")
#define SCHEDB  __builtin_amdgcn_sched_barrier(0)

// one kh-half-tile: 1024 chunks of 16B; 2 global_load_lds per thread.
// LDS dest linear in lane order (gl_lds requirement); global src is
// inverse-swizzled so the read-side XOR sees data in place (rule 21).
__device__ __forceinline__ void stage_half(const _Float16* __restrict__ g,
                                           _Float16* lb, int t, int kbase)
{
    #pragma unroll
    for (int j = 0; j < 2; ++j) {
        const int c   = t + j * 512;
        const int row = c >> 2;
        const int ch  = (c & 3) ^ ((row >> 1) & 3);
        gl2lds16(g + (size_t)row * KE_ + kbase + ch * 8, lb + c * 8);
    }
}

template<int DB, int KH, int MQ>
__device__ __forceinline__ void ds_load_a(const _Float16* lds, int wave_m, int s,
                                          int quad, half8 (&a)[4]) {
    const _Float16* base = lds + (DB * 4 + KH) * 8192;
    #pragma unroll
    for (int mi = 0; mi < 4; ++mi) {
        int row = wave_m * 128 + MQ * 64 + mi * 16 + s;
        int ch  = quad ^ ((row >> 1) & 3);
        a[mi] = *(const half8*)(base + row * 32 + ch * 8);
    }
}

template<int DB, int KH>
__device__ __forceinline__ void ds_load_b(const _Float16* lds, int wave_n, int s,
                                          int quad, half8 (&bfr)[4]) {
    const _Float16* base = lds + (DB * 4 + 2 + KH) * 8192;
    #pragma unroll
    for (int ni = 0; ni < 4; ++ni) {
        int col = wave_n * 64 + ni * 16 + s;
        int ch  = quad ^ ((col >> 1) & 3);
        bfr[ni] = *(const half8*)(base + col * 32 + ch * 8);
    }
}

template<int MQ>
__device__ __forceinline__ void do_mfma(const half8 (&a)[4], const half8 (&bfr)[4],
                                        floatx4 (&acc)[8][4]) {
    __builtin_amdgcn_s_setprio(1);
    #pragma unroll
    for (int mi = 0; mi < 4; ++mi)
        #pragma unroll
        for (int ni = 0; ni < 4; ++ni)
            acc[MQ * 4 + mi][ni] = __builtin_amdgcn_mfma_f32_16x16x32_f16(
                a[mi], bfr[ni], acc[MQ * 4 + mi][ni], 0, 0, 0);
    __builtin_amdgcn_s_setprio(0);
}

__global__ __launch_bounds__(512, 1) void gemm_mfma_kernel(
    const _Float16* __restrict__ Aexp, const _Float16* __restrict__ Bexp,
    float* __restrict__ out0, unsigned long long* __restrict__ keys)
{
    __shared__ __align__(16) _Float16 lds[65536];   // 128 KiB, 2x double-buffered K-tiles

    const int t      = threadIdx.x;
    const int lane   = t & 63;
    const int wave   = t >> 6;
    const int quad   = lane >> 4;
    const int s      = lane & 15;
    const int wave_m = wave >> 2;     // 0..1 -> 128 output rows
    const int wave_n = wave & 3;      // 0..3 -> 64 output cols

    // T1: XCD-bijective swizzle. HW assigns block n -> XCD n%8; give each
    // XCD a contiguous 128-wgid chunk (one batch, 8 qt-rows, all kt).
    const int n    = blockIdx.x;
    const int wgid = (n & 7) * 128 + (n >> 3);
    const int kt   = wgid & 15;
    const int qt   = (wgid >> 4) & 15;
    const int b    = wgid >> 8;

    const _Float16* Agl = Aexp + (size_t)b * HW_ * KE_ + (size_t)(qt * 256) * KE_;
    const _Float16* Bgl = Bexp + (size_t)b * HW_ * KE_ + (size_t)(kt * 256) * KE_;

    // Prologue: tile0 complete (db0) + tile1 kh0 (db1); vmcnt(4) leaves the
    // last 2 half-tiles (tile1 kh0) in flight, tile0 fully staged.
    stage_half(Agl, lds + 0 * 8192, t, 0);
    stage_half(Bgl, lds + 2 * 8192, t, 0);
    stage_half(Agl, lds + 1 * 8192, t, 32);
    stage_half(Bgl, lds + 3 * 8192, t, 32);
    stage_half(Agl, lds + 4 * 8192, t, 64);
    stage_half(Bgl, lds + 6 * 8192, t, 64);
    VMC(4);
    BARRIER; SCHEDB;

    half8 a[4], bfr[4];
    floatx4 acc[8][4] = {};

    // Main loop: iteration computes tiles 2it (db0) and 2it+1 (db1) and
    // stages tiles 2it+1(kh1), 2it+2(all), 2it+3(kh0). vmcnt(4) only at
    // phases 3 and 7 -> 2 half-tiles stay in flight across barriers.
    #pragma unroll 1
    for (int it = 0; it < 5; ++it) {
        const int kb1 = (2 * it + 1) * 64;
        const int kb2 = kb1 + 64;
        const int kb3 = kb1 + 128;
        // p0: compute db0/kh0/mq0, stage A(T+1)-kh1 -> region 5
        ds_load_a<0, 0, 0>(lds, wave_m, s, quad, a);
        ds_load_b<0, 0>(lds, wave_n, s, quad, bfr);
        stage_half(Agl, lds + 5 * 8192, t, kb1 + 32);
        BARRIER; LGKM0;
        do_mfma<0>(a, bfr, acc);
        BARRIER;
        // p1: db0/kh0/mq1 (reuse bfr), stage B(T+1)-kh1 -> region 7
        ds_load_a<0, 0, 1>(lds, wave_m, s, quad, a);
        stage_half(Bgl, lds + 7 * 8192, t, kb1 + 32);
        BARRIER; LGKM0;
        do_mfma<1>(a, bfr, acc);
        BARRIER;
        // p2: db0/kh1/mq0, stage A(T+2)-kh0 -> region 0
        ds_load_a<0, 1, 0>(lds, wave_m, s, quad, a);
        ds_load_b<0, 1>(lds, wave_n, s, quad, bfr);
        stage_half(Agl, lds + 0 * 8192, t, kb2);
        BARRIER; LGKM0;
        do_mfma<0>(a, bfr, acc);
        BARRIER;
        // p3: db0/kh1/mq1, stage B(T+2)-kh0 -> region 2 ; VMC(4): db1 ready
        ds_load_a<0, 1, 1>(lds, wave_m, s, quad, a);
        stage_half(Bgl, lds + 2 * 8192, t, kb2);
        BARRIER; LGKM0;
        do_mfma<1>(a, bfr, acc);
        VMC(4);
        BARRIER; SCHEDB;
        // p4: db1/kh0/mq0, stage A(T+2)-kh1 -> region 1
        ds_load_a<1, 0, 0>(lds, wave_m, s, quad, a);
        ds_load_b<1, 0>(lds, wave_n, s, quad, bfr);
        stage_half(Agl, lds + 1 * 8192, t, kb2 + 32);
        BARRIER; LGKM0;
        do_mfma<0>(a, bfr, acc);
        BARRIER;
        // p5: db1/kh0/mq1, stage B(T+2)-kh1 -> region 3
        ds_load_a<1, 0, 1>(lds, wave_m, s, quad, a);
        stage_half(Bgl, lds + 3 * 8192, t, kb2 + 32);
        BARRIER; LGKM0;
        do_mfma<1>(a, bfr, acc);
        BARRIER;
        // p6: db1/kh1/mq0, stage A(T+3)-kh0 -> region 4
        ds_load_a<1, 1, 0>(lds, wave_m, s, quad, a);
        ds_load_b<1, 1>(lds, wave_n, s, quad, bfr);
        stage_half(Agl, lds + 4 * 8192, t, kb3);
        BARRIER; LGKM0;
        do_mfma<0>(a, bfr, acc);
        BARRIER;
        // p7: db1/kh1/mq1, stage B(T+3)-kh0 -> region 6 ; VMC(4): db0(T+2) ready
        ds_load_a<1, 1, 1>(lds, wave_m, s, quad, a);
        stage_half(Bgl, lds + 6 * 8192, t, kb3);
        BARRIER; LGKM0;
        do_mfma<1>(a, bfr, acc);
        VMC(4);
        BARRIER; SCHEDB;
    }

    // ---- Drain-then-compute tail: tiles 10 (db0) & 11 (db1) ----
    // Stage the one missing half-tile (tile11 kh1), drain ALL outstanding
    // loads, sync once. After this point LDS is read-only: no barriers or
    // hand waitcnts needed — compiler dependency tracking is sufficient.
    stage_half(Agl, lds + 5 * 8192, t, 736);
    stage_half(Bgl, lds + 7 * 8192, t, 736);
    VMC(0);
    __syncthreads();

    ds_load_a<0, 0, 0>(lds, wave_m, s, quad, a);
    ds_load_b<0, 0>(lds, wave_n, s, quad, bfr);
    do_mfma<0>(a, bfr, acc);
    ds_load_a<0, 0, 1>(lds, wave_m, s, quad, a);
    do_mfma<1>(a, bfr, acc);
    ds_load_a<0, 1, 0>(lds, wave_m, s, quad, a);
    ds_load_b<0, 1>(lds, wave_n, s, quad, bfr);
    do_mfma<0>(a, bfr, acc);
    ds_load_a<0, 1, 1>(lds, wave_m, s, quad, a);
    do_mfma<1>(a, bfr, acc);
    ds_load_a<1, 0, 0>(lds, wave_m, s, quad, a);
    ds_load_b<1, 0>(lds, wave_n, s, quad, bfr);
    do_mfma<0>(a, bfr, acc);
    ds_load_a<1, 0, 1>(lds, wave_m, s, quad, a);
    do_mfma<1>(a, bfr, acc);
    ds_load_a<1, 1, 0>(lds, wave_m, s, quad, a);
    ds_load_b<1, 1>(lds, wave_n, s, quad, bfr);
    do_mfma<0>(a, bfr, acc);
    ds_load_a<1, 1, 1>(lds, wave_m, s, quad, a);
    do_mfma<1>(a, bfr, acc);

    // ---- Epilogue 1: S_vis corner (C/D layout: col=s, row=quad*4+r) ----
    if (qt < 4 && kt < 4) {
        #pragma unroll
        for (int mi8 = 0; mi8 < 8; ++mi8)
            #pragma unroll
            for (int r = 0; r < 4; ++r) {
                int grow = qt * 256 + wave_m * 128 + mi8 * 16 + quad * 4 + r;
                float* orow = out0 + ((size_t)b * VIS_ + grow) * VIS_ + kt * 256 + wave_n * 64;
                #pragma unroll
                for (int ni = 0; ni < 4; ++ni)
                    orow[ni * 16 + s] = acc[mi8][ni][r];
            }
    }

    // ---- Epilogue 2: fused argmax; alias reduction array onto staging LDS ----
    __syncthreads();
    unsigned long long* red = (unsigned long long*)lds;   // [256 rows][4 wave_n]

    #pragma unroll
    for (int mi8 = 0; mi8 < 8; ++mi8) {
        #pragma unroll
        for (int r = 0; r < 4; ++r) {
            float best = acc[mi8][0][r];
            int bcol = wave_n * 64 + s;
            #pragma unroll
            for (int ni = 1; ni < 4; ++ni) {
                float v = acc[mi8][ni][r];
                if (v > best) { best = v; bcol = wave_n * 64 + ni * 16 + s; }
            }
            int gcol = kt * 256 + bcol;
            unsigned long long key = ((unsigned long long)mapf(best) << 32)
                                   | (unsigned)(HW_ - 1 - gcol);
            #pragma unroll
            for (int m = 1; m < 16; m <<= 1) {
                unsigned long long o = __shfl_xor(key, m, 64);
                if (o > key) key = o;
            }
            if (s == 0)
                red[(wave_m * 128 + mi8 * 16 + quad * 4 + r) * 4 + wave_n] = key;
        }
    }
    __syncthreads();
    if (t < 256) {
        const unsigned long long* rr = red + t * 4;
        unsigned long long k0 = rr[0], k1 = rr[1], k2 = rr[2], k3 = rr[3];
        unsigned long long m01 = k0 > k1 ? k0 : k1;
        unsigned long long m23 = k2 > k3 ? k2 : k3;
        atomicMax(&keys[(size_t)b * HW_ + qt * 256 + t], m01 > m23 ? m01 : m23);
    }
}

// ---------------- fp32 fallback path (round-1, known-good) ----------------
#define BT   64
#define BK   32
#define LDP  68

__global__ __launch_bounds__(256) void gemm_argmax_kernel(
    const float* __restrict__ Q, const float* __restrict__ K,
    float* __restrict__ out0, unsigned long long* __restrict__ ws)
{
    __shared__ float As[BK][LDP];
    __shared__ float Bs[BK][LDP];
    __shared__ unsigned long long red[BT][17];

    const int t  = threadIdx.x;
    const int tx = t & 15;
    const int ty = t >> 4;
    const int k0 = blockIdx.x * BT;
    const int q0 = blockIdx.y * BT;
    const int b  = blockIdx.z;

    const float* Qb = Q + (size_t)b * C_ * HW_;
    const float* Kb = K + (size_t)b * C_ * HW_;

    float acc[4][4] = {{0.f},{0.f},{0.f},{0.f}};

    for (int c0 = 0; c0 < C_; c0 += BK) {
        #pragma unroll
        for (int i = 0; i < 2; ++i) {
            int idx = i * 256 + t;
            int row = idx >> 4;
            int col = (idx & 15) * 4;
            const float4 a  = *(const float4*)(Qb + (size_t)(c0 + row) * HW_ + q0 + col);
            const float4 bv = *(const float4*)(Kb + (size_t)(c0 + row) * HW_ + k0 + col);
            *(float4*)(&As[row][col]) = a;
            *(float4*)(&Bs[row][col]) = bv;
        }
        __syncthreads();
        #pragma unroll
        for (int cc = 0; cc < BK; ++cc) {
            const float4 av = *(const float4*)(&As[cc][ty * 4]);
            const float4 bv = *(const float4*)(&Bs[cc][tx * 4]);
            const float a_[4] = {av.x, av.y, av.z, av.w};
            const float b_[4] = {bv.x, bv.y, bv.z, bv.w};
            #pragma unroll
            for (int i = 0; i < 4; ++i)
                #pragma unroll
                for (int j = 0; j < 4; ++j)
                    acc[i][j] = fmaf(a_[i], b_[j], acc[i][j]);
        }
        __syncthreads();
    }

    if (q0 < VIS_ && k0 < VIS_) {
        #pragma unroll
        for (int i = 0; i < 4; ++i) {
            float4 v = make_float4(acc[i][0], acc[i][1], acc[i][2], acc[i][3]);
            size_t off = (size_t)b * VIS_ * VIS_ + (size_t)(q0 + ty * 4 + i) * VIS_ + (k0 + tx * 4);
            *(float4*)(out0 + off) = v;
        }
    }

    #pragma unroll
    for (int i = 0; i < 4; ++i) {
        float best = acc[i][0];
        int   bj   = 0;
        #pragma unroll
        for (int j = 1; j < 4; ++j)
            if (acc[i][j] > best) { best = acc[i][j]; bj = j; }
        int kidx = k0 + tx * 4 + bj;
        unsigned long long key = ((unsigned long long)mapf(best) << 32)
                               | (unsigned)(HW_ - 1 - kidx);
        red[ty * 4 + i][tx] = key;
    }
    __syncthreads();
    if (t < BT) {
        unsigned long long best = red[t][0];
        #pragma unroll
        for (int j = 1; j < 16; ++j) {
            unsigned long long v = red[t][j];
            if (v > best) best = v;
        }
        atomicMax(&ws[(size_t)b * HW_ + q0 + t], best);
    }
}

extern "C" void kernel_launch(void* const* d_in, const int* in_sizes, int n_in,
                              void* d_out, int out_size, void* d_ws, size_t ws_size,
                              hipStream_t stream) {
    const float* Q = (const float*)d_in[0];
    const float* K = (const float*)d_in[1];
    float* out0 = (float*)d_out;
    float* out1 = out0 + (size_t)B_ * VIS_ * VIS_;

    unsigned long long* keys = (unsigned long long*)d_ws;     // 128 KB
    const size_t keys_bytes = (size_t)B_ * HW_ * 8;
    const size_t exp_elems  = (size_t)B_ * HW_ * KE_;
    const size_t need = keys_bytes + 2 * exp_elems * sizeof(_Float16);

    const int n = B_ * HW_;

    if (ws_size >= need) {
        _Float16* Aexp = (_Float16*)((char*)d_ws + keys_bytes);
        _Float16* Bexp = Aexp + exp_elems;
        split_transpose_kernel<<<dim3(HW_ / 64, C_ / 64, 2 * B_), 256, 0, stream>>>(Q, K, Aexp, Bexp, keys);
        gemm_mfma_kernel<<<dim3((HW_ / 256) * (HW_ / 256) * B_), 512, 0, stream>>>(Aexp, Bexp, out0, keys);
    } else {
        init_ws_kernel<<<(n + 255) / 256, 256, 0, stream>>>(keys, n);
        gemm_argmax_kernel<<<dim3(HW_ / BT, HW_ / BT, B_), 256, 0, stream>>>(Q, K, out0, keys);
    }

    finalize_kernel<<<(n + 255) / 256, 256, 0, stream>>>(keys, out1, n);
}

// Round 5
// 214.889 us; speedup vs baseline: 1.2161x; 1.0204x over previous
//
#include <hip/hip_runtime.h>
#include <stdint.h>

// Problem constants: B=4, C=256, H=W=64 -> HW=4096, vis=1024
#define B_   4
#define C_   256
#define HW_  4096
#define VIS_ 1024
#define KE_  768      // expanded K: [hi,hi,lo] x [hi,lo,hi] f16 split

using half8   = __attribute__((ext_vector_type(8))) _Float16;
using floatx4 = __attribute__((ext_vector_type(4))) float;

__device__ __forceinline__ unsigned mapf(float v) {
    unsigned u = __float_as_uint(v);
    return (u & 0x80000000u) ? ~u : (u | 0x80000000u);
}

__global__ void init_ws_kernel(unsigned long long* ws, int n) {
    int i = blockIdx.x * blockDim.x + threadIdx.x;
    if (i < n) ws[i] = 0ull;
}

__global__ void finalize_kernel(const unsigned long long* __restrict__ ws,
                                float* __restrict__ out1, int n) {
    int i = blockIdx.x * blockDim.x + threadIdx.x;
    if (i < n) {
        unsigned kinv = (unsigned)(ws[i] & 0xFFFFFFFFull);
        out1[i] = (float)(HW_ - 1 - (int)kinv);
    }
}

// ---------------- f16-split MFMA path ----------------

// Transpose + split: src[b][c][hw] fp32 -> dst[b][hw][768] f16 with
// A segments [hi,hi,lo], B segments [hi,lo,hi]. Also zeroes the keys
// workspace (fused init: blocks with y==0&&z==0 cover exactly B_*HW_ keys).
__global__ __launch_bounds__(256) void split_transpose_kernel(
    const float* __restrict__ Q, const float* __restrict__ K,
    _Float16* __restrict__ Aexp, _Float16* __restrict__ Bexp,
    unsigned long long* __restrict__ keys)
{
    __shared__ float tile[64][65];   // [c][hw], pad 65 to break 8-col bank aliasing
    const int t = threadIdx.x;
    if (blockIdx.y == 0 && blockIdx.z == 0)
        keys[blockIdx.x * 256 + t] = 0ull;   // 64 blocks x 256 thr = 16384 = B_*HW_

    const int hw0 = blockIdx.x * 64;
    const int c0  = blockIdx.y * 64;
    const int z = blockIdx.z, b = z >> 1, which = z & 1;
    const float* src = (which ? K : Q) + (size_t)b * C_ * HW_;
    _Float16* dst = (which ? Bexp : Aexp) + (size_t)b * HW_ * KE_;

    #pragma unroll
    for (int i = 0; i < 4; ++i) {
        int c  = (t >> 4) + i * 16;
        int hw = (t & 15) * 4;
        float4 v = *(const float4*)(src + (size_t)(c0 + c) * HW_ + hw0 + hw);
        tile[c][hw] = v.x; tile[c][hw+1] = v.y; tile[c][hw+2] = v.z; tile[c][hw+3] = v.w;
    }
    __syncthreads();

    #pragma unroll
    for (int i = 0; i < 2; ++i) {
        int id  = t + i * 256;       // 0..511
        int row = id >> 3;           // hw within tile
        int c8  = (id & 7) * 8;      // c offset within 64
        half8 h8, l8;
        #pragma unroll
        for (int j = 0; j < 8; ++j) {
            float v = tile[c8 + j][row];
            _Float16 h = (_Float16)v;
            h8[j] = h;
            l8[j] = (_Float16)(v - (float)h);
        }
        _Float16* base = dst + (size_t)(hw0 + row) * KE_ + c0 + c8;
        *(half8*)(base + 0 * C_) = h8;
        *(half8*)(base + 1 * C_) = which ? l8 : h8;
        *(half8*)(base + 2 * C_) = which ? h8 : l8;
    }
}

__device__ __forceinline__ void gl2lds16(const _Float16* g, _Float16* l) {
    __builtin_amdgcn_global_load_lds(
        (const __attribute__((address_space(1))) void*)g,
        (__attribute__((address_space(3))) void*)l, 16, 0, 0);
}

// ---- 256x256 / BK=32 quad-buffered / counted-vmcnt GEMM ----
//
// Round-5 change vs round 4: same per-phase rates (16 MFMA, 8-or-4
// ds_read_b128, 1 stage_half, 2 barriers) but K-step 32 with FOUR
// A/B buffers (8 regions x 16 KB = 128 KiB). Tile T+3 is staged during
// tile T, so VMC(8) leaves 4 half-tiles (64 KB) in flight (was 2/32 KB)
// and stage->forced-landed slack grows 3 -> 4-5 phases, covering L3/HBM
// latency at a faster pipeline pace.
//
// Region map (f16 units, 16 KB regions): A(db) = lds + (db*2+0)*8192,
// B(db) = lds + (db*2+1)*8192, db = T & 3. Tile T holds k-range
// [T*32, T*32+32). 24 tiles total; main loop T=0..20 (stages T+3 <= 23),
// tail tiles 21..23 run after a full drain, barrier-free (LDS read-only).
//
// RAW: tile T staged at T-3; forced landed at (T-1).q1's VMC(8)
//      (outstanding there = tiles T-1, T-2 batches = exactly 8 newest).
// WAR: region (T+3)&3 last read at tile T-1, >=2 barriers before T stages.
// Chunk swizzle (involution on 16B chunks within a 64B row):
//   lds chunk (row, ch) holds global chunk ch ^ ((row>>1)&3)

#define BARRIER __builtin_amdgcn_s_barrier()
#define LGKM0   asm volatile("s_waitcnt lgkmcnt(0)" ::: "memory")
#define VMC(n)  asm volatile("s_waitcnt vmcnt(" #n ")" ::: "memory")
#define SCHEDB  __builtin_amdgcn_sched_barrier(0)

// one 256x32 half-tile: 1024 chunks of 16B; 2 global_load_lds per thread.
// LDS dest linear in lane order (gl_lds requirement); global src is
// inverse-swizzled so the read-side XOR sees data in place (rule 21).
__device__ __forceinline__ void stage_half(const _Float16* __restrict__ g,
                                           _Float16* lb, int t, int kbase)
{
    #pragma unroll
    for (int j = 0; j < 2; ++j) {
        const int c   = t + j * 512;
        const int row = c >> 2;
        const int ch  = (c & 3) ^ ((row >> 1) & 3);
        gl2lds16(g + (size_t)row * KE_ + kbase + ch * 8, lb + c * 8);
    }
}

template<int MQ>
__device__ __forceinline__ void ds_load_a(const _Float16* base, int wave_m, int s,
                                          int quad, half8 (&a)[4]) {
    #pragma unroll
    for (int mi = 0; mi < 4; ++mi) {
        int row = wave_m * 128 + MQ * 64 + mi * 16 + s;
        int ch  = quad ^ ((row >> 1) & 3);
        a[mi] = *(const half8*)(base + row * 32 + ch * 8);
    }
}

__device__ __forceinline__ void ds_load_b(const _Float16* base, int wave_n, int s,
                                          int quad, half8 (&bfr)[4]) {
    #pragma unroll
    for (int ni = 0; ni < 4; ++ni) {
        int col = wave_n * 64 + ni * 16 + s;
        int ch  = quad ^ ((col >> 1) & 3);
        bfr[ni] = *(const half8*)(base + col * 32 + ch * 8);
    }
}

template<int MQ>
__device__ __forceinline__ void do_mfma(const half8 (&a)[4], const half8 (&bfr)[4],
                                        floatx4 (&acc)[8][4]) {
    __builtin_amdgcn_s_setprio(1);
    #pragma unroll
    for (int mi = 0; mi < 4; ++mi)
        #pragma unroll
        for (int ni = 0; ni < 4; ++ni)
            acc[MQ * 4 + mi][ni] = __builtin_amdgcn_mfma_f32_16x16x32_f16(
                a[mi], bfr[ni], acc[MQ * 4 + mi][ni], 0, 0, 0);
    __builtin_amdgcn_s_setprio(0);
}

__global__ __launch_bounds__(512, 1) void gemm_mfma_kernel(
    const _Float16* __restrict__ Aexp, const _Float16* __restrict__ Bexp,
    float* __restrict__ out0, unsigned long long* __restrict__ keys)
{
    __shared__ __align__(16) _Float16 lds[65536];   // 128 KiB = 8 regions x 16 KB

    const int t      = threadIdx.x;
    const int lane   = t & 63;
    const int wave   = t >> 6;
    const int quad   = lane >> 4;
    const int s      = lane & 15;
    const int wave_m = wave >> 2;     // 0..1 -> 128 output rows
    const int wave_n = wave & 3;      // 0..3 -> 64 output cols

    // T1: XCD-bijective swizzle (kept from round 4; harmless).
    const int n    = blockIdx.x;
    const int wgid = (n & 7) * 128 + (n >> 3);
    const int kt   = wgid & 15;
    const int qt   = (wgid >> 4) & 15;
    const int b    = wgid >> 8;

    const _Float16* Agl = Aexp + (size_t)b * HW_ * KE_ + (size_t)(qt * 256) * KE_;
    const _Float16* Bgl = Bexp + (size_t)b * HW_ * KE_ + (size_t)(kt * 256) * KE_;

    // Prologue: stage tiles 0,1,2 (12 loads); VMC(8) forces tile 0 landed,
    // leaves tiles 1,2 (4 half-tiles) in flight.
    stage_half(Agl, lds + 0 * 8192, t, 0);
    stage_half(Bgl, lds + 1 * 8192, t, 0);
    stage_half(Agl, lds + 2 * 8192, t, 32);
    stage_half(Bgl, lds + 3 * 8192, t, 32);
    stage_half(Agl, lds + 4 * 8192, t, 64);
    stage_half(Bgl, lds + 5 * 8192, t, 64);
    VMC(8);
    BARRIER; SCHEDB;

    half8 a[4], bfr[4];
    floatx4 acc[8][4] = {};

    // Main loop: tile T (db = T&3), stages tile T+3 (db3 = (T+3)&3).
    // 2 phases per tile; VMC(8) once per tile at q1.
    #pragma unroll 1
    for (int T = 0; T < 21; ++T) {
        const int db  = T & 3;
        const int db3 = (T + 3) & 3;
        const _Float16* Ar = lds + (db * 2 + 0) * 8192;
        const _Float16* Br = lds + (db * 2 + 1) * 8192;
        _Float16* As = lds + (db3 * 2 + 0) * 8192;
        _Float16* Bs = lds + (db3 * 2 + 1) * 8192;
        const int kb3 = (T + 3) * 32;

        // q0: compute mq0, stage A(T+3)
        ds_load_a<0>(Ar, wave_m, s, quad, a);
        ds_load_b(Br, wave_n, s, quad, bfr);
        stage_half(Agl, As, t, kb3);
        BARRIER; LGKM0;
        do_mfma<0>(a, bfr, acc);
        BARRIER;
        // q1: compute mq1 (reuse bfr), stage B(T+3); VMC(8): tile T+1 ready
        ds_load_a<1>(Ar, wave_m, s, quad, a);
        stage_half(Bgl, Bs, t, kb3);
        BARRIER; LGKM0;
        do_mfma<1>(a, bfr, acc);
        VMC(8);
        BARRIER; SCHEDB;
    }

    // ---- Drain-then-compute tail: tiles 21,22,23 (all staged, in flight) ----
    VMC(0);
    __syncthreads();

    #pragma unroll
    for (int T = 21; T < 24; ++T) {
        const _Float16* Ar = lds + ((T & 3) * 2 + 0) * 8192;
        const _Float16* Br = lds + ((T & 3) * 2 + 1) * 8192;
        ds_load_a<0>(Ar, wave_m, s, quad, a);
        ds_load_b(Br, wave_n, s, quad, bfr);
        do_mfma<0>(a, bfr, acc);
        ds_load_a<1>(Ar, wave_m, s, quad, a);
        do_mfma<1>(a, bfr, acc);
    }

    // ---- Epilogue 1: S_vis corner (C/D layout: col=s, row=quad*4+r) ----
    if (qt < 4 && kt < 4) {
        #pragma unroll
        for (int mi8 = 0; mi8 < 8; ++mi8)
            #pragma unroll
            for (int r = 0; r < 4; ++r) {
                int grow = qt * 256 + wave_m * 128 + mi8 * 16 + quad * 4 + r;
                float* orow = out0 + ((size_t)b * VIS_ + grow) * VIS_ + kt * 256 + wave_n * 64;
                #pragma unroll
                for (int ni = 0; ni < 4; ++ni)
                    orow[ni * 16 + s] = acc[mi8][ni][r];
            }
    }

    // ---- Epilogue 2: fused argmax; alias reduction array onto staging LDS ----
    __syncthreads();
    unsigned long long* red = (unsigned long long*)lds;   // [256 rows][4 wave_n]

    #pragma unroll
    for (int mi8 = 0; mi8 < 8; ++mi8) {
        #pragma unroll
        for (int r = 0; r < 4; ++r) {
            float best = acc[mi8][0][r];
            int bcol = wave_n * 64 + s;
            #pragma unroll
            for (int ni = 1; ni < 4; ++ni) {
                float v = acc[mi8][ni][r];
                if (v > best) { best = v; bcol = wave_n * 64 + ni * 16 + s; }
            }
            int gcol = kt * 256 + bcol;
            unsigned long long key = ((unsigned long long)mapf(best) << 32)
                                   | (unsigned)(HW_ - 1 - gcol);
            #pragma unroll
            for (int m = 1; m < 16; m <<= 1) {
                unsigned long long o = __shfl_xor(key, m, 64);
                if (o > key) key = o;
            }
            if (s == 0)
                red[(wave_m * 128 + mi8 * 16 + quad * 4 + r) * 4 + wave_n] = key;
        }
    }
    __syncthreads();
    if (t < 256) {
        const unsigned long long* rr = red + t * 4;
        unsigned long long k0 = rr[0], k1 = rr[1], k2 = rr[2], k3 = rr[3];
        unsigned long long m01 = k0 > k1 ? k0 : k1;
        unsigned long long m23 = k2 > k3 ? k2 : k3;
        atomicMax(&keys[(size_t)b * HW_ + qt * 256 + t], m01 > m23 ? m01 : m23);
    }
}

// ---------------- fp32 fallback path (round-1, known-good) ----------------
#define BT   64
#define BK   32
#define LDP  68

__global__ __launch_bounds__(256) void gemm_argmax_kernel(
    const float* __restrict__ Q, const float* __restrict__ K,
    float* __restrict__ out0, unsigned long long* __restrict__ ws)
{
    __shared__ float As[BK][LDP];
    __shared__ float Bs[BK][LDP];
    __shared__ unsigned long long red[BT][17];

    const int t  = threadIdx.x;
    const int tx = t & 15;
    const int ty = t >> 4;
    const int k0 = blockIdx.x * BT;
    const int q0 = blockIdx.y * BT;
    const int b  = blockIdx.z;

    const float* Qb = Q + (size_t)b * C_ * HW_;
    const float* Kb = K + (size_t)b * C_ * HW_;

    float acc[4][4] = {{0.f},{0.f},{0.f},{0.f}};

    for (int c0 = 0; c0 < C_; c0 += BK) {
        #pragma unroll
        for (int i = 0; i < 2; ++i) {
            int idx = i * 256 + t;
            int row = idx >> 4;
            int col = (idx & 15) * 4;
            const float4 a  = *(const float4*)(Qb + (size_t)(c0 + row) * HW_ + q0 + col);
            const float4 bv = *(const float4*)(Kb + (size_t)(c0 + row) * HW_ + k0 + col);
            *(float4*)(&As[row][col]) = a;
            *(float4*)(&Bs[row][col]) = bv;
        }
        __syncthreads();
        #pragma unroll
        for (int cc = 0; cc < BK; ++cc) {
            const float4 av = *(const float4*)(&As[cc][ty * 4]);
            const float4 bv = *(const float4*)(&Bs[cc][tx * 4]);
            const float a_[4] = {av.x, av.y, av.z, av.w};
            const float b_[4] = {bv.x, bv.y, bv.z, bv.w};
            #pragma unroll
            for (int i = 0; i < 4; ++i)
                #pragma unroll
                for (int j = 0; j < 4; ++j)
                    acc[i][j] = fmaf(a_[i], b_[j], acc[i][j]);
        }
        __syncthreads();
    }

    if (q0 < VIS_ && k0 < VIS_) {
        #pragma unroll
        for (int i = 0; i < 4; ++i) {
            float4 v = make_float4(acc[i][0], acc[i][1], acc[i][2], acc[i][3]);
            size_t off = (size_t)b * VIS_ * VIS_ + (size_t)(q0 + ty * 4 + i) * VIS_ + (k0 + tx * 4);
            *(float4*)(out0 + off) = v;
        }
    }

    #pragma unroll
    for (int i = 0; i < 4; ++i) {
        float best = acc[i][0];
        int   bj   = 0;
        #pragma unroll
        for (int j = 1; j < 4; ++j)
            if (acc[i][j] > best) { best = acc[i][j]; bj = j; }
        int kidx = k0 + tx * 4 + bj;
        unsigned long long key = ((unsigned long long)mapf(best) << 32)
                               | (unsigned)(HW_ - 1 - kidx);
        red[ty * 4 + i][tx] = key;
    }
    __syncthreads();
    if (t < BT) {
        unsigned long long best = red[t][0];
        #pragma unroll
        for (int j = 1; j < 16; ++j) {
            unsigned long long v = red[t][j];
            if (v > best) best = v;
        }
        atomicMax(&ws[(size_t)b * HW_ + q0 + t], best);
    }
}

extern "C" void kernel_launch(void* const* d_in, const int* in_sizes, int n_in,
                              void* d_out, int out_size, void* d_ws, size_t ws_size,
                              hipStream_t stream) {
    const float* Q = (const float*)d_in[0];
    const float* K = (const float*)d_in[1];
    float* out0 = (float*)d_out;
    float* out1 = out0 + (size_t)B_ * VIS_ * VIS_;

    unsigned long long* keys = (unsigned long long*)d_ws;     // 128 KB
    const size_t keys_bytes = (size_t)B_ * HW_ * 8;
    const size_t exp_elems  = (size_t)B_ * HW_ * KE_;
    const size_t need = keys_bytes + 2 * exp_elems * sizeof(_Float16);

    const int n = B_ * HW_;

    if (ws_size >= need) {
        _Float16* Aexp = (_Float16*)((char*)d_ws + keys_bytes);
        _Float16* Bexp = Aexp + exp_elems;
        split_transpose_kernel<<<dim3(HW_ / 64, C_ / 64, 2 * B_), 256, 0, stream>>>(Q, K, Aexp, Bexp, keys);
        gemm_mfma_kernel<<<dim3((HW_ / 256) * (HW_ / 256) * B_), 512, 0, stream>>>(Aexp, Bexp, out0, keys);
    } else {
        init_ws_kernel<<<(n + 255) / 256, 256, 0, stream>>>(keys, n);
        gemm_argmax_kernel<<<dim3(HW_ / BT, HW_ / BT, B_), 256, 0, stream>>>(Q, K, out0, keys);
    }

    finalize_kernel<<<(n + 255) / 256, 256, 0, stream>>>(keys, out1, n);
}